// Round 1
// baseline (1030.566 us; speedup 1.0000x reference)
//
#include <hip/hip_runtime.h>
#include <math.h>

// Problem constants
#define S_LEN 2048
#define EMB   1024
#define NH    16
#define HD    64
#define BATCH 2
#define MROWS (BATCH * S_LEN)   // 4096

// ---------------------------------------------------------------------------
// sin/cos table:  sintab[s*32+p] = sin(s * inv_freq[p]),  p = 0..31
// Matches JAX fp32 semantics: inv_freq rounded to fp32, product rounded to
// fp32, then accurate sin/cos of that fp32 angle.
// ---------------------------------------------------------------------------
__global__ void sincos_kernel(float* __restrict__ sintab, float* __restrict__ costab)
{
    int i = blockIdx.x * blockDim.x + threadIdx.x;   // 0 .. 65535
    if (i >= S_LEN * (HD / 2)) return;
    int s = i >> 5;
    int p = i & 31;
    double invd = exp(-((double)(2 * p) / (double)HD) * log(10000.0));
    float  invf = (float)invd;
    float  ang  = (float)s * invf;     // fp32 rounding, same as jnp einsum
    sintab[i] = (float)sin((double)ang);
    costab[i] = (float)cos((double)ang);
}

__device__ __forceinline__ void f4_to_arr(float4 v, float* a)
{
    a[0] = v.x; a[1] = v.y; a[2] = v.z; a[3] = v.w;
}

// ---------------------------------------------------------------------------
// Shared fp32 GEMM core: computes a 64x64 tile of  X(M,1024) @ W(1024,1024)^T
// acc[i][j] = sum_k X[m0+4*ty+i][k] * W[n0+4*tx+j][k]
// 256 threads, 4x4 per thread, BK=16.  All inner-loop LDS reads are b128.
// ---------------------------------------------------------------------------
__device__ __forceinline__ void fc_core_64x64(const float* __restrict__ X,
                                              const float* __restrict__ W,
                                              int m0, int n0,
                                              float acc[4][4])
{
    __shared__ float As[64][20];    // [m][k], pad 20 keeps b128 16B-aligned
    __shared__ float BsT[16][68];   // [k][n] (transposed W tile)

    const int t  = threadIdx.x;
    const int tx = t & 15;
    const int ty = t >> 4;
    const int lr = t >> 2;          // 0..63 : row loaded by this thread
    const int lk = (t & 3) << 2;    // 0,4,8,12 : k-offset loaded

    for (int k0 = 0; k0 < EMB; k0 += 16) {
        const float4 av = *(const float4*)(X + (size_t)(m0 + lr) * EMB + k0 + lk);
        const float4 wv = *(const float4*)(W + (size_t)(n0 + lr) * EMB + k0 + lk);
        __syncthreads();            // previous iteration's reads complete
        *(float4*)(&As[lr][lk]) = av;
        BsT[lk + 0][lr] = wv.x;
        BsT[lk + 1][lr] = wv.y;
        BsT[lk + 2][lr] = wv.z;
        BsT[lk + 3][lr] = wv.w;
        __syncthreads();

        #pragma unroll
        for (int kk = 0; kk < 16; kk += 4) {
            float a[4][4], bb[4][4];
            #pragma unroll
            for (int i = 0; i < 4; ++i)
                f4_to_arr(*(const float4*)(&As[4 * ty + i][kk]), a[i]);
            #pragma unroll
            for (int u = 0; u < 4; ++u)
                f4_to_arr(*(const float4*)(&BsT[kk + u][4 * tx]), bb[u]);
            #pragma unroll
            for (int u = 0; u < 4; ++u)
                #pragma unroll
                for (int i = 0; i < 4; ++i)
                    #pragma unroll
                    for (int j = 0; j < 4; ++j)
                        acc[i][j] = fmaf(a[i][u], bb[u][j], acc[i][j]);
        }
    }
}

// ---------------------------------------------------------------------------
// QKV projection + bias + RoPE(Q,K) + fold softmax scale into Q.
// Writes [B, H, S, HD].  blockIdx.z selects Q / K / V.
// ---------------------------------------------------------------------------
__global__ __launch_bounds__(256) void qkv_kernel(
    const float* __restrict__ X,
    const float* __restrict__ Wq, const float* __restrict__ Wk, const float* __restrict__ Wv,
    const float* __restrict__ bq, const float* __restrict__ bk, const float* __restrict__ bv,
    float* __restrict__ qo, float* __restrict__ ko, float* __restrict__ vo,
    const float* __restrict__ sintab, const float* __restrict__ costab)
{
    const int mode = blockIdx.z;                 // 0=Q 1=K 2=V
    const float* W    = (mode == 0) ? Wq : (mode == 1) ? Wk : Wv;
    const float* bias = (mode == 0) ? bq : (mode == 1) ? bk : bv;
    float*       out  = (mode == 0) ? qo : (mode == 1) ? ko : vo;

    const int m0 = blockIdx.y * 64;
    const int n0 = blockIdx.x * 64;

    float acc[4][4] = {};
    fc_core_64x64(X, W, m0, n0, acc);

    const int t  = threadIdx.x;
    const int tx = t & 15;
    const int ty = t >> 4;
    const int nc = n0 + 4 * tx;                  // column in E
    const int h  = nc >> 6;
    const int d  = nc & 63;                      // multiple of 4 -> even pair start
    const float b0 = bias[nc], b1 = bias[nc + 1], b2 = bias[nc + 2], b3 = bias[nc + 3];
    const float scl = (mode == 0) ? 0.125f : 1.0f;   // HD^-0.5 folded into Q

    #pragma unroll
    for (int i = 0; i < 4; ++i) {
        const int m  = m0 + 4 * ty + i;
        const int bi = m >> 11;                  // batch
        const int s  = m & (S_LEN - 1);
        float x0 = acc[i][0] + b0;
        float x1 = acc[i][1] + b1;
        float x2 = acc[i][2] + b2;
        float x3 = acc[i][3] + b3;
        if (mode < 2) {
            const int p0 = d >> 1;
            const float sn0 = sintab[s * 32 + p0],     cs0 = costab[s * 32 + p0];
            const float sn1 = sintab[s * 32 + p0 + 1], cs1 = costab[s * 32 + p0 + 1];
            // e2 = e*cos - o*sin ;  o2 = e2*sin + o*cos   (exact reference form)
            const float e2a = x0 * cs0 - x1 * sn0;
            const float o2a = e2a * sn0 + x1 * cs0;
            const float e2b = x2 * cs1 - x3 * sn1;
            const float o2b = e2b * sn1 + x3 * cs1;
            x0 = e2a * scl; x1 = o2a * scl; x2 = e2b * scl; x3 = o2b * scl;
        }
        *(float4*)(out + ((((size_t)bi * NH + h) * S_LEN + s) << 6) + d) =
            make_float4(x0, x1, x2, x3);
    }
}

// ---------------------------------------------------------------------------
// Output projection: ctx(M,1024) @ Wo^T + bo -> out[M,1024]
// ---------------------------------------------------------------------------
__global__ __launch_bounds__(256) void out_kernel(
    const float* __restrict__ Xc,
    const float* __restrict__ Wo, const float* __restrict__ bo,
    float* __restrict__ out)
{
    const int m0 = blockIdx.y * 64;
    const int n0 = blockIdx.x * 64;
    float acc[4][4] = {};
    fc_core_64x64(Xc, Wo, m0, n0, acc);

    const int t  = threadIdx.x;
    const int tx = t & 15;
    const int ty = t >> 4;
    const int nc = n0 + 4 * tx;
    const float b0 = bo[nc], b1 = bo[nc + 1], b2 = bo[nc + 2], b3 = bo[nc + 3];

    #pragma unroll
    for (int i = 0; i < 4; ++i) {
        const int m = m0 + 4 * ty + i;
        *(float4*)(out + (size_t)m * EMB + nc) =
            make_float4(acc[i][0] + b0, acc[i][1] + b1, acc[i][2] + b2, acc[i][3] + b3);
    }
}

// ---------------------------------------------------------------------------
// Flash attention, fp32.  One block per (q-tile of 64 rows, h, b).
// Q pre-scaled by HD^-0.5.  K stored transposed in LDS (b128 score reads);
// P tile aliases the K buffer.  Online softmax state per row, replicated
// across the 16 tx lanes via shfl_xor butterflies (rows live in one wave).
// ---------------------------------------------------------------------------
__global__ __launch_bounds__(256) void attn_kernel(
    const float* __restrict__ q, const float* __restrict__ k,
    const float* __restrict__ v, float* __restrict__ ctx)
{
    const int qt = blockIdx.x;                   // 0..31
    const int h  = blockIdx.y;
    const int b  = blockIdx.z;
    const size_t baseQ = (((size_t)b * NH + h) * S_LEN + (size_t)qt * 64) * HD;
    const size_t baseK = (((size_t)b * NH + h) * S_LEN) * HD;

    __shared__ float Qt[64][68];
    __shared__ float KP[64 * 68];    // K transposed [d][r] stride 68; reused as P [r][ks] stride 68
    __shared__ float Vt[64][68];

    const int t    = threadIdx.x;
    const int tx   = t & 15;
    const int ty   = t >> 4;
    const int lane = t & 63;
    const int wv   = t >> 6;

    // ---- load Q tile (row-major, coalesced) ----
    #pragma unroll
    for (int it = 0; it < 4; ++it) {
        const int r = (t >> 4) + 16 * it;
        const int c = (t & 15) * 4;
        *(float4*)(&Qt[r][c]) = *(const float4*)(q + baseQ + r * 64 + c);
    }

    float m_run[4], l_run[4], o[4][4];
    #pragma unroll
    for (int i = 0; i < 4; ++i) {
        m_run[i] = -INFINITY;
        l_run[i] = 0.0f;
        #pragma unroll
        for (int j = 0; j < 4; ++j) o[i][j] = 0.0f;
    }

    for (int kt = 0; kt < S_LEN / 64; ++kt) {
        const size_t kb = baseK + (size_t)kt * 64 * 64;

        __syncthreads();   // previous PV reads of KP/Vt done (also Q load on iter 0)

        // K tile, transposed: KP[d*68 + r] = K[r][d]
        #pragma unroll
        for (int it = 0; it < 4; ++it) {
            const int d0 = 4 * wv + 16 * it;
            const float4 kv = *(const float4*)(k + kb + (size_t)lane * 64 + d0);
            KP[(d0 + 0) * 68 + lane] = kv.x;
            KP[(d0 + 1) * 68 + lane] = kv.y;
            KP[(d0 + 2) * 68 + lane] = kv.z;
            KP[(d0 + 3) * 68 + lane] = kv.w;
        }
        // V tile, row-major
        #pragma unroll
        for (int it = 0; it < 4; ++it) {
            const int r = (t >> 4) + 16 * it;
            const int c = (t & 15) * 4;
            *(float4*)(&Vt[r][c]) = *(const float4*)(v + kb + r * 64 + c);
        }
        __syncthreads();

        // ---- scores: sc[i][j] = sum_d Q[4ty+i][d] * K[4tx+j][d] ----
        float sc[4][4] = {};
        #pragma unroll
        for (int d0 = 0; d0 < 64; d0 += 4) {
            float a[4][4], bb[4][4];
            #pragma unroll
            for (int i = 0; i < 4; ++i)
                f4_to_arr(*(const float4*)(&Qt[4 * ty + i][d0]), a[i]);
            #pragma unroll
            for (int u = 0; u < 4; ++u)
                f4_to_arr(*(const float4*)(&KP[(d0 + u) * 68 + 4 * tx]), bb[u]);
            #pragma unroll
            for (int u = 0; u < 4; ++u)
                #pragma unroll
                for (int i = 0; i < 4; ++i)
                    #pragma unroll
                    for (int j = 0; j < 4; ++j)
                        sc[i][j] = fmaf(a[i][u], bb[u][j], sc[i][j]);
        }

        // ---- online softmax ----
        float mt[4], al[4], rs[4];
        #pragma unroll
        for (int i = 0; i < 4; ++i)
            mt[i] = fmaxf(fmaxf(sc[i][0], sc[i][1]), fmaxf(sc[i][2], sc[i][3]));
        #pragma unroll
        for (int off = 1; off < 16; off <<= 1)
            #pragma unroll
            for (int i = 0; i < 4; ++i)
                mt[i] = fmaxf(mt[i], __shfl_xor(mt[i], off));
        #pragma unroll
        for (int i = 0; i < 4; ++i) {
            const float mn = fmaxf(m_run[i], mt[i]);
            al[i] = __expf(m_run[i] - mn);
            m_run[i] = mn;
        }
        #pragma unroll
        for (int i = 0; i < 4; ++i) {
            float s0 = __expf(sc[i][0] - m_run[i]);
            float s1 = __expf(sc[i][1] - m_run[i]);
            float s2 = __expf(sc[i][2] - m_run[i]);
            float s3 = __expf(sc[i][3] - m_run[i]);
            sc[i][0] = s0; sc[i][1] = s1; sc[i][2] = s2; sc[i][3] = s3;
            rs[i] = (s0 + s1) + (s2 + s3);
        }
        #pragma unroll
        for (int off = 1; off < 16; off <<= 1)
            #pragma unroll
            for (int i = 0; i < 4; ++i)
                rs[i] += __shfl_xor(rs[i], off);
        #pragma unroll
        for (int i = 0; i < 4; ++i) {
            l_run[i] = l_run[i] * al[i] + rs[i];
            #pragma unroll
            for (int j = 0; j < 4; ++j) o[i][j] *= al[i];
        }

        __syncthreads();   // all K reads done -> safe to overwrite KP with P
        #pragma unroll
        for (int i = 0; i < 4; ++i)
            *(float4*)(&KP[(4 * ty + i) * 68 + 4 * tx]) =
                make_float4(sc[i][0], sc[i][1], sc[i][2], sc[i][3]);
        __syncthreads();

        // ---- PV: o[i][j] += sum_ks P[4ty+i][ks] * V[ks][4tx+j] ----
        #pragma unroll
        for (int ks = 0; ks < 64; ks += 4) {
            float pa[4][4], vb[4][4];
            #pragma unroll
            for (int i = 0; i < 4; ++i)
                f4_to_arr(*(const float4*)(&KP[(4 * ty + i) * 68 + ks]), pa[i]);
            #pragma unroll
            for (int u = 0; u < 4; ++u)
                f4_to_arr(*(const float4*)(&Vt[ks + u][4 * tx]), vb[u]);
            #pragma unroll
            for (int u = 0; u < 4; ++u)
                #pragma unroll
                for (int i = 0; i < 4; ++i)
                    #pragma unroll
                    for (int j = 0; j < 4; ++j)
                        o[i][j] = fmaf(pa[i][u], vb[u][j], o[i][j]);
        }
    }

    // ---- normalize and write ctx [B, S, E] ----
    #pragma unroll
    for (int i = 0; i < 4; ++i) {
        const float inv = 1.0f / l_run[i];
        const int   s   = qt * 64 + 4 * ty + i;
        *(float4*)(ctx + ((size_t)b * S_LEN + s) * EMB + h * 64 + 4 * tx) =
            make_float4(o[i][0] * inv, o[i][1] * inv, o[i][2] * inv, o[i][3] * inv);
    }
}

// ---------------------------------------------------------------------------
// Launch
// ---------------------------------------------------------------------------
extern "C" void kernel_launch(void* const* d_in, const int* in_sizes, int n_in,
                              void* d_out, int out_size, void* d_ws, size_t ws_size,
                              hipStream_t stream)
{
    (void)in_sizes; (void)n_in; (void)out_size; (void)ws_size;

    const float* X  = (const float*)d_in[0];
    const float* Wq = (const float*)d_in[1];
    const float* bq = (const float*)d_in[2];
    const float* Wk = (const float*)d_in[3];
    const float* bk = (const float*)d_in[4];
    const float* Wv = (const float*)d_in[5];
    const float* bv = (const float*)d_in[6];
    const float* Wo = (const float*)d_in[7];
    const float* bo = (const float*)d_in[8];
    float* out = (float*)d_out;

    // Workspace layout (floats): sin 65536 | cos 65536 | q,k,v,ctx 4x4194304
    // Total = 67,633,152 bytes.
    float* ws     = (float*)d_ws;
    float* sintab = ws;
    float* costab = ws + 65536;
    float* qb     = ws + 131072;
    float* kb     = qb + (size_t)MROWS * EMB;
    float* vb     = kb + (size_t)MROWS * EMB;
    float* ctx    = vb + (size_t)MROWS * EMB;

    hipLaunchKernelGGL(sincos_kernel, dim3(256), dim3(256), 0, stream, sintab, costab);
    hipLaunchKernelGGL(qkv_kernel, dim3(EMB / 64, MROWS / 64, 3), dim3(256), 0, stream,
                       X, Wq, Wk, Wv, bq, bk, bv, qb, kb, vb, sintab, costab);
    hipLaunchKernelGGL(attn_kernel, dim3(S_LEN / 64, NH, BATCH), dim3(256), 0, stream,
                       qb, kb, vb, ctx);
    hipLaunchKernelGGL(out_kernel, dim3(EMB / 64, MROWS / 64), dim3(256), 0, stream,
                       ctx, Wo, bo, out);
}